// Round 11
// baseline (136.985 us; speedup 1.0000x reference)
//
#include <hip/hip_runtime.h>

// Autoregressive LSTM log-prob via MFMA, 8-wave split-cell (R10 structure,
// issue-trimmed). B=4096, L=256, H=32, D=2. 256 WGs x 512 threads, 16
// batches/WG, 1 WG/CU, 2 waves/SIMD.
// gates^T = Wh^T @ h^T; wave w (rot=w&3, half=w>>2) computes the 4 gate
// tiles of its unit half, row-rotated so its ONE cell/lane is acc reg 0.
// R11 trims: spins as packed bits (1 ds_read_b32 / 32 steps, compile-time
// bit extracts), 32-step static unroll (t runs 1..256; step 256 is a dead
// step whose MFMA feeds the step-255 head — all blocks identical, no tail),
// 2log2e folded into the cell state (c' = 2L*c, one less chain mul).
// One barrier per step. Logits raw in LDS; ELU+log-softmax+reduce post-loop.

typedef __attribute__((ext_vector_type(8))) short bf16x8;
typedef __attribute__((ext_vector_type(4))) float f32x4;

#define LOG2E  1.4426950408889634f
#define TWOL   2.8853900817779268f
#define LN2    0.6931471805599453f

__device__ __forceinline__ float fexp2(float x) { return __builtin_amdgcn_exp2f(x); }
__device__ __forceinline__ float flog2(float x) { return __builtin_amdgcn_logf(x); }
__device__ __forceinline__ float frcp(float x)  { return __builtin_amdgcn_rcpf(x); }

__device__ __forceinline__ float fsig(float x)   { return frcp(1.f + fexp2(-LOG2E * x)); }
__device__ __forceinline__ float ftanh_(float x) { return 1.f - 2.f * frcp(fexp2(TWOL * x) + 1.f); }
__device__ __forceinline__ float felu(float x)   { return x > 0.f ? x : fexp2(LOG2E * x) - 1.f; }

__device__ __forceinline__ unsigned short f2bf(float f) {   // RNE f32->bf16
    unsigned u = __builtin_bit_cast(unsigned, f);
    u = (u + 0x7FFFu + ((u >> 16) & 1u)) >> 16;
    return (unsigned short)u;
}

constexpr int Bsz = 4096;

__global__ __launch_bounds__(512, 2) void lstm_r11(
    const int*   __restrict__ x,    // [B, 256]
    const float* __restrict__ Wi,   // [2, 128]
    const float* __restrict__ Wh,   // [32, 128]
    const float* __restrict__ bh,   // [128]
    const float* __restrict__ Wo,   // [32, 2]
    const float* __restrict__ bo,   // [2]
    float*       __restrict__ out)  // [B]
{
    const int tid  = threadIdx.x;
    const int w    = tid >> 6;      // wave 0..7
    const int lane = tid & 63;
    const int m    = lane & 15;     // batch column
    const int oct  = lane >> 4;
    const int rot  = w & 3;         // gate-row rotation
    const int half = w >> 2;        // unit half
    const int b0   = blockIdx.x * 16;

    __shared__ unsigned spinbits[16][8];  // [batch][word]: spin t = bit t
    __shared__ float2   Sbuf[256][16];    // raw logits (S0,S1) per (t,batch)
    __shared__ short    hbuf[2][16][40];  // h dbuf, row stride 80 B
    __shared__ float    red[8][16];

    // ---- stage spins as packed bits: thread -> (batch tid>>5, 8 ints -> 1 byte)
    {
        const int bl = tid >> 5;
        const int c8 = (tid & 31) * 8;
        const int4* src = reinterpret_cast<const int4*>(x + (b0 + bl) * 256 + c8);
        const int4 v0 = src[0], v1 = src[1];
        const unsigned bv =
            (v0.x & 1) | ((v0.y & 1) << 1) | ((v0.z & 1) << 2) | ((v0.w & 1) << 3) |
            ((v1.x & 1) << 4) | ((v1.y & 1) << 5) | ((v1.z & 1) << 6) | ((v1.w & 1) << 7);
        reinterpret_cast<char*>(spinbits)[bl * 32 + (tid & 31)] = (char)bv;
    }

    // ---- weight A-frags: 4 tiles (gate q, unit-half), rows rotated by rot
    bf16x8 wfrag[4];
#pragma unroll
    for (int q = 0; q < 4; ++q) {
        const float gs = (q == 2) ? TWOL * 0.5f * 2.f : -LOG2E;   // g: 2log2e, else -log2e
        const float gss = (q == 2) ? TWOL : -LOG2E;
        (void)gs;
        const int colg = 32 * q + 16 * half + ((m + rot) & 15);
#pragma unroll
        for (int j = 0; j < 8; ++j)
            wfrag[q][j] = (short)f2bf(((q == 2) ? TWOL * 0.5f : -LOG2E) * 2.f * 0.5f * Wh[(oct * 8 + j) * 128 + colg] * ((q == 2) ? 2.f : 1.f) / ((q == 2) ? 2.f : 1.f) * ((q == 2) ? 2.f : 1.f));
        (void)gss;
    }
    // NOTE: the expression above must reduce to gs = (q==2 ? 2*log2e : -log2e);
    // rewrite cleanly to avoid any doubt:
#pragma unroll
    for (int q = 0; q < 4; ++q) {
        const float gs = (q == 2) ? (2.f * LOG2E) : -LOG2E;
        const int colg = 32 * q + 16 * half + ((m + rot) & 15);
#pragma unroll
        for (int j = 0; j < 8; ++j)
            wfrag[q][j] = (short)f2bf(gs * Wh[(oct * 8 + j) * 128 + colg]);
    }
    bf16x8 wofragA;   // head: Wo^T padded to 16 rows
#pragma unroll
    for (int j = 0; j < 8; ++j)
        wofragA[j] = (m < 2) ? (short)f2bf(Wo[(oct * 8 + j) * 2 + m]) : (short)0;

    // ---- this lane's cell + scaled biases ----
    const int ucell = 4 * oct + rot + 16 * half;
    float bv0[4], bvd[4];
#pragma unroll
    for (int q = 0; q < 4; ++q) {
        const float gs = (q == 2) ? (2.f * LOG2E) : -LOG2E;
        const int c0 = 32 * q + ucell;
        bv0[q] = gs * (bh[c0] + Wi[c0]);
        bvd[q] = gs * (Wi[128 + c0] - Wi[c0]);
    }
    const float bo0 = bo[0], bo1 = bo[1];

    // ---- peel t=0: input zeros, h=c=0 -> gates = bh. State kept as c' = 2L*c.
    float cp = TWOL * (fsig(bh[ucell]) * ftanh_(bh[64 + ucell]));
    hbuf[0][m][ucell] = (short)f2bf(fsig(bh[96 + ucell]) * ftanh_(cp * (1.f / TWOL)));
    __syncthreads();

    const f32x4 zero4 = { 0.f, 0.f, 0.f, 0.f };
    f32x4 ccq[4] = { zero4, zero4, zero4, zero4 };   // persistent C quads

    // ---- main loop: 8 blocks x 32 static steps; t = 32k+1+i runs 1..256.
    // Step 256 is dead work except its hfrag (= h_255) feeds the step-255 head.
    unsigned cur = spinbits[m][0];
    for (int k = 0; k < 8; ++k) {
        const int tb = 32 * k + 1;
        const unsigned nxt = spinbits[m][k < 7 ? k + 1 : 7];
#pragma unroll
        for (int i = 0; i < 32; ++i) {
            const int rb = i & 1, wb = rb ^ 1;
            const float spf = (float)((cur >> i) & 1u);   // spin_{t-1}, static shift

            const bf16x8 hfrag =
                *reinterpret_cast<const bf16x8*>(&hbuf[rb][m][8 * oct]);

            // bias (bh + Wi[spin_{t-1}]) into C reg 0 — off the MFMA chain
#pragma unroll
            for (int q = 0; q < 4; ++q) ccq[q][0] = fmaf(spf, bvd[q], bv0[q]);

            f32x4 acc[4];
#pragma unroll
            for (int q = 0; q < 4; ++q)
                acc[q] = __builtin_amdgcn_mfma_f32_16x16x32_bf16(wfrag[q], hfrag, ccq[q], 0, 0, 0);

            // head logits of step t-1: duty rotates with i (wave-uniform branch)
            if ((i & 7) == w) {
                const f32x4 hacc =
                    __builtin_amdgcn_mfma_f32_16x16x32_bf16(wofragA, hfrag, zero4, 0, 0, 0);
                if (oct == 0) Sbuf[tb - 1 + i][m] = make_float2(hacc[0], hacc[1]);
            }

            // cell update; e_i=e^{-i}, e_f=e^{-f}, e_g=e^{2g}, e_o=e^{-o};
            // state c' = 2L*c so tanh(c) uses exp2(c') with no extra mul.
            {
                const float ei = fexp2(acc[0][0]), ef = fexp2(acc[1][0]);
                const float eg = fexp2(acc[2][0]), eo = fexp2(acc[3][0]);
                const float P  = (1.f + ei) * (1.f + eg);
                const float Q  = 1.f + ef;
                const float E  = fmaf(eg, TWOL, -TWOL);   // 2L*(eg-1)
                const float R  = frcp(P * Q);
                const float gf   = P * R;                 // 1/(1+ef)
                const float igtp = E * Q * R;             // 2L * sig(i)*tanh(g)
                cp = fmaf(gf, cp, igtp);
                const float ec = fexp2(cp);               // e^{2c}
                const float h  = (ec - 1.f) * frcp((1.f + eo) * (1.f + ec));
                hbuf[wb][m][ucell] = (short)f2bf(h);
            }
            __syncthreads();
        }
        cur = nxt;
    }

    // ---- post phase: ELU + log-softmax + sum over t, 32 time-chunks ----
    float lp = 0.f;
    {
        const unsigned sw = spinbits[m][w] >> (8 * oct);   // my 8 spin bits
        const int t0 = w * 32 + oct * 8;
#pragma unroll
        for (int i = 0; i < 8; ++i) {
            const int t = t0 + i;
            const float2 sv = Sbuf[t][m];
            const int sp = (sw >> i) & 1u;
            const float o0 = felu(sv.x + bo0);
            const float o1 = felu(sv.y + bo1);
            const float mx = fmaxf(o0, o1), mn = fminf(o0, o1);
            const float lse = mx + LN2 * flog2(1.f + fexp2(LOG2E * (mn - mx)));
            lp += (sp ? o1 : o0) - lse;
        }
    }
    lp += __shfl_xor(lp, 16, 64);   // reduce over oct
    lp += __shfl_xor(lp, 32, 64);
    if (lane < 16) red[w][lane] = lp;
    __syncthreads();
    if (tid < 16) {
        float s = 0.f;
#pragma unroll
        for (int ww = 0; ww < 8; ++ww) s += red[ww][tid];
        out[b0 + tid] = 0.5f * s;
    }
}

extern "C" void kernel_launch(void* const* d_in, const int* in_sizes, int n_in,
                              void* d_out, int out_size, void* d_ws, size_t ws_size,
                              hipStream_t stream) {
    const int*   x  = (const int*)d_in[0];
    const float* Wi = (const float*)d_in[1];
    const float* Wh = (const float*)d_in[2];
    const float* bh = (const float*)d_in[3];
    const float* Wo = (const float*)d_in[4];
    const float* bo = (const float*)d_in[5];
    float* out = (float*)d_out;

    lstm_r11<<<dim3(Bsz / 16), dim3(512), 0, stream>>>(x, Wi, Wh, bh, Wo, bo, out);
}